// Round 12
// baseline (10956.493 us; speedup 1.0000x reference)
//
#include <hip/hip_runtime.h>
#include <stdint.h>

// GRU scan, persistent cooperative kernel, round 12.
// = round 8's proven single-flag schedule (one post + one vmcnt(0) drain per
// step — rounds 9/11 proved a second mid-step drain costs more than the skew
// saves) + three ledger fixes:
//   1) x(t+1) prefetch issued at J AFTER the drain+post -> no vmcnt(0) ever
//      waits on HBM; x retires across the step boundary (used at next C).
//   2) flags preloaded at J (before x in issue order -> A's wait is a counted
//      vmcnt(6), no fresh poll RTT when producers already posted).
//   3) mid-step wait is counted vmcnt(4) (hi staged; lo-stores uncounted) —
//      no mid drain. 2 barriers/step.
// Topology: 32 clusters x 32 batch rows x 8 blocks, NT=256, wave owns 16 cols,
// all W_hh in regs (static idx), LDS = 32KB A-tile. Coherence: write-through
// h stores (RELAXED/AGENT), aux=17 read-through staging, relaxed per-wave
// flags, no fences. Anti-race: own-block waves included in the 32-word flag
// poll; each wave posts only after its last LDS read (logits) of the step.

#define NB 256
#define NT 256
#define TB 1024
#define TT 2048
#define II 12
#define HH 512
#define NCL 32
#define ROWS 32

#define HTILE_B (ROWS * HH * 2)               // 32 KiB per cluster per buffer
#define HBUF_B  ((size_t)NCL * HTILE_B)       // 1 MiB per buffer
#define BAR_OFF ((size_t)2 * HBUF_B)
#define WS_USED (BAR_OFF + (size_t)NCL * 128) // 32 flag words per cluster

#define LDSB (ROWS * 1024)                    // 32 KiB A-tile

#define GAS __attribute__((address_space(1)))
#define LAS __attribute__((address_space(3)))

typedef _Float16 half8 __attribute__((ext_vector_type(8)));
typedef float    f32x4 __attribute__((ext_vector_type(4)));

static __device__ __forceinline__ float fast_sigmoid(float x) {
  float e = exp2f(-1.44269504f * x);
  return __builtin_amdgcn_rcpf(1.0f + e);
}
static __device__ __forceinline__ float fast_tanh(float x) {
  float e = exp2f(2.88539008f * x);           // exp(2x)
  return 1.0f - 2.0f * __builtin_amdgcn_rcpf(1.0f + e);
}

// Blocking poll of 32 per-wave flag words, lane-parallel, relaxed agent.
static __device__ __forceinline__ void wait_flags32(unsigned* f, unsigned tgt,
                                                    int* dead) {
  const int l = threadIdx.x & 63;
  long spin = 0;
  for (;;) {
    unsigned v = __hip_atomic_load(f + (l & 31), __ATOMIC_RELAXED,
                                   __HIP_MEMORY_SCOPE_AGENT);
    if (__all(v >= tgt)) break;
    if (++spin > (1L << 24)) { *dead = 1; break; }
  }
}

__global__ void __launch_bounds__(NT, 1)
gru_persistent(const float* __restrict__ hist,
               const float* __restrict__ w_ih,
               const float* __restrict__ w_hh,
               const float* __restrict__ w_out,
               const float* __restrict__ b_out,
               float* __restrict__ out,
               uint8_t* __restrict__ ws)
{
  extern __shared__ char smem[];
  char* ldsA = smem;
  const int bid = blockIdx.x;
  const int c   = bid & 31;          // cluster (32)
  const int g   = bid >> 5;          // block within cluster (8)
  const int tid = threadIdx.x;
  const int w   = tid >> 6;          // wave 0..3 -> col-tile
  const int l   = tid & 63;
  const int l15 = l & 15;
  const int l4  = l >> 4;
  const int crb = c * ROWS;
  unsigned* F = (unsigned*)(ws + BAR_OFF) + (size_t)c * 32;   // 32 words
  const int myflag = g * 4 + w;

  const int col0 = g * 64 + w * 16;  // wave's 16 output cols
  const int pcol = col0 + l15;

  // ---- W_hh register B-fragments for r,z,n (16 K-slices each, static idx)
  half8 wr[16], wz[16], wn[16];
#pragma unroll
  for (int ks = 0; ks < 16; ++ks) {
    const size_t Rr = (size_t)(0 * HH + col0 + l15) * HH + ks * 32 + l4 * 8;
    const size_t Rz = (size_t)(1 * HH + col0 + l15) * HH + ks * 32 + l4 * 8;
    const size_t Rn = (size_t)(2 * HH + col0 + l15) * HH + ks * 32 + l4 * 8;
#pragma unroll
    for (int i = 0; i < 8; ++i) {
      wr[ks][i] = (_Float16)w_hh[Rr + i];
      wz[ks][i] = (_Float16)w_hh[Rz + i];
      wn[ks][i] = (_Float16)w_hh[Rn + i];
    }
  }

  // ---- w_ih register B-fragments (K window = x cols 0..31)
  half8 wih[3];
#pragma unroll
  for (int gt = 0; gt < 3; ++gt) {
    const int R = gt * HH + col0 + l15;
#pragma unroll
    for (int i = 0; i < 8; ++i) {
      const int k = l4 * 8 + i;
      wih[gt][i] = (_Float16)((k < II) ? w_ih[R * II + k] : 0.0f);
    }
  }

  // ---- logits: wave myflag -> rows erow and 16+erow, output jj;
  //      lane l holds w_out[jj][l*8 .. l*8+7]; full 64-lane reduce
  const int jj   = myflag & 1;
  const int erow = myflag >> 1;
  float wor8[8];
#pragma unroll
  for (int i = 0; i < 8; ++i) wor8[i] = w_out[jj * HH + l * 8 + i];
  const float bo = b_out[jj];

  float hprev[2][4];
#pragma unroll
  for (int mt = 0; mt < 2; ++mt)
#pragma unroll
    for (int q = 0; q < 4; ++q) hprev[mt][q] = 0.0f;

  int deadlock = 0;

  // ---- prologue: issue x(0) prefetch (NOT drained — ledger matches loop)
  f32x4 xn0[2], xn1[2];
#pragma unroll
  for (int mt = 0; mt < 2; ++mt) {
    xn0[mt] = (f32x4){0.f, 0.f, 0.f, 0.f};
    xn1[mt] = (f32x4){0.f, 0.f, 0.f, 0.f};
    const float* xp = hist + (size_t)(crb + mt * 16 + l15) * (TT * II);
    if (l4 == 0)      { xn0[mt] = *(const f32x4*)xp; xn1[mt] = *(const f32x4*)(xp + 4); }
    else if (l4 == 1) { xn0[mt] = *(const f32x4*)(xp + 8); }
  }

  unsigned preF = 0;

  for (int t = 0; t < TT; ++t) {
    const uint8_t* hsrc = ws + ((t & 1) ? HBUF_B : 0) + (size_t)c * HTILE_B;
    uint8_t*       hdst = ws + ((t & 1) ? 0 : HBUF_B) + (size_t)c * HTILE_B;

    // A: wait flags(t) — preloaded at J (counted wait, usually free)
    if (t > 0) {
      if (!__all(preF >= (unsigned)t)) wait_flags32(F, (unsigned)t, &deadlock);
    }
    __builtin_amdgcn_sched_barrier(0);

    // B: issue full stage rows 0-31 (8 insts; lo = first 4)   [out: x6 + s8]
#pragma unroll
    for (int it = 0; it < 8; ++it)
      __builtin_amdgcn_global_load_lds(
          (const GAS uint32_t*)(hsrc + it * 4096 + tid * 16),
          (LAS uint32_t*)(ldsA + it * 4096 + tid * 16), 16, 0, 17);
    __builtin_amdgcn_sched_barrier(0);

    // C: build ax from x regs (compiler waits x only: vmcnt(8))
    half8 ax[2];
#pragma unroll
    for (int mt = 0; mt < 2; ++mt)
#pragma unroll
      for (int i = 0; i < 4; ++i) {
        ax[mt][i]     = (_Float16)xn0[mt][i];
        ax[mt][4 + i] = (_Float16)xn1[mt][i];
      }
    __builtin_amdgcn_sched_barrier(0);

    // E: vmcnt(4) -> lo staged (hi 4 outstanding) -> barrier
    asm volatile("s_waitcnt vmcnt(4)" ::: "memory");
    __builtin_amdgcn_s_barrier();
    __builtin_amdgcn_sched_barrier(0);

    // ======== phase 1: rows 0-15 (mt=0) ========
    f32x4 acc0 = (f32x4){0.f, 0.f, 0.f, 0.f};
    f32x4 acc1 = acc0, acc2 = acc0;
    f32x4 accin = __builtin_amdgcn_mfma_f32_16x16x32_f16(ax[0], wih[2],
                    (f32x4){0.f, 0.f, 0.f, 0.f}, 0, 0, 0);
    acc0 = __builtin_amdgcn_mfma_f32_16x16x32_f16(ax[0], wih[0], acc0, 0, 0, 0);
    acc1 = __builtin_amdgcn_mfma_f32_16x16x32_f16(ax[0], wih[1], acc1, 0, 0, 0);
#pragma unroll
    for (int ks = 0; ks < 16; ++ks) {
      const int ko = (ks * 64 + l4 * 16) ^ ((l15 & 7) << 4);
      half8 a = *(const half8*)(ldsA + l15 * 1024 + ko);
      acc0 = __builtin_amdgcn_mfma_f32_16x16x32_f16(a, wr[ks], acc0, 0, 0, 0);
      acc1 = __builtin_amdgcn_mfma_f32_16x16x32_f16(a, wz[ks], acc1, 0, 0, 0);
      acc2 = __builtin_amdgcn_mfma_f32_16x16x32_f16(a, wn[ks], acc2, 0, 0, 0);
    }

    // G: gates + stores rows 0-15                    [out: hi-s4 + st4]
#pragma unroll
    for (int q = 0; q < 4; ++q) {
      const int m = l4 * 4 + q;
      const float r  = fast_sigmoid(acc0[q]);
      const float z  = fast_sigmoid(acc1[q]);
      const float n  = fast_tanh(accin[q] + r * acc2[q]);
      const float hn = (1.0f - z) * n + z * hprev[0][q];
      hprev[0][q] = hn;
      __hip_atomic_store(
          (unsigned short*)(hdst + m * 1024 + ((pcol * 2) ^ ((m & 7) << 4))),
          __builtin_bit_cast(unsigned short, (_Float16)hn),
          __ATOMIC_RELAXED, __HIP_MEMORY_SCOPE_AGENT);
    }
    __builtin_amdgcn_sched_barrier(0);

    // mid: vmcnt(4) -> hi staged (lo-stores uncounted) -> barrier
    asm volatile("s_waitcnt vmcnt(4)" ::: "memory");
    __builtin_amdgcn_s_barrier();
    __builtin_amdgcn_sched_barrier(0);

    // ======== phase 2: rows 16-31 (mt=1) ========
    acc0 = (f32x4){0.f, 0.f, 0.f, 0.f};
    acc1 = acc0; acc2 = acc0;
    accin = __builtin_amdgcn_mfma_f32_16x16x32_f16(ax[1], wih[2],
              (f32x4){0.f, 0.f, 0.f, 0.f}, 0, 0, 0);
    acc0 = __builtin_amdgcn_mfma_f32_16x16x32_f16(ax[1], wih[0], acc0, 0, 0, 0);
    acc1 = __builtin_amdgcn_mfma_f32_16x16x32_f16(ax[1], wih[1], acc1, 0, 0, 0);
#pragma unroll
    for (int ks = 0; ks < 16; ++ks) {
      const int ko = (ks * 64 + l4 * 16) ^ ((l15 & 7) << 4);
      half8 a = *(const half8*)(ldsA + (16 + l15) * 1024 + ko);
      acc0 = __builtin_amdgcn_mfma_f32_16x16x32_f16(a, wr[ks], acc0, 0, 0, 0);
      acc1 = __builtin_amdgcn_mfma_f32_16x16x32_f16(a, wz[ks], acc1, 0, 0, 0);
      acc2 = __builtin_amdgcn_mfma_f32_16x16x32_f16(a, wn[ks], acc2, 0, 0, 0);
    }
#pragma unroll
    for (int q = 0; q < 4; ++q) {
      const int m = 16 + l4 * 4 + q;
      const float r  = fast_sigmoid(acc0[q]);
      const float z  = fast_sigmoid(acc1[q]);
      const float n  = fast_tanh(accin[q] + r * acc2[q]);
      const float hn = (1.0f - z) * n + z * hprev[1][q];
      hprev[1][q] = hn;
      __hip_atomic_store(
          (unsigned short*)(hdst + m * 1024 + ((pcol * 2) ^ ((m & 7) << 4))),
          __builtin_bit_cast(unsigned short, (_Float16)hn),
          __ATOMIC_RELAXED, __HIP_MEMORY_SCOPE_AGENT);
    }

    // logits(t-1): rows erow and 16+erow (both halves staged & stable; last
    // LDS reads of this step -> precede our flag post -> anti-race holds)
    if (t > 0) {
#pragma unroll
      for (int half = 0; half < 2; ++half) {
        const int lrw = half * 16 + erow;
        float s = 0.0f;
        half8 hv = *(const half8*)(ldsA + lrw * 1024 + ((l * 16) ^ ((lrw & 7) << 4)));
#pragma unroll
        for (int i = 0; i < 8; ++i) s += (float)hv[i] * wor8[i];
#pragma unroll
        for (int off = 1; off < 64; off <<= 1) s += __shfl_xor(s, off);
        if (l == 0) out[((size_t)(crb + lrw) * TT + (t - 1)) * 2 + jj] = s + bo;
      }
    }
    __builtin_amdgcn_sched_barrier(0);

    // J: drain 8 h-stores (no x in ledger) -> post -> preload F -> issue x
    asm volatile("s_waitcnt vmcnt(0)" ::: "memory");
    __builtin_amdgcn_sched_barrier(0);
    if (l == 0)
      __hip_atomic_store(F + myflag, (unsigned)(t + 1), __ATOMIC_RELAXED,
                         __HIP_MEMORY_SCOPE_AGENT);
    preF = __hip_atomic_load(F + (l & 31), __ATOMIC_RELAXED,
                             __HIP_MEMORY_SCOPE_AGENT);
    __builtin_amdgcn_sched_barrier(0);
    {
      const int tx = (t + 1 < TT) ? (t + 1) : 0;
#pragma unroll
      for (int mt = 0; mt < 2; ++mt) {
        const float* xp = hist + (size_t)(crb + mt * 16 + l15) * (TT * II) + (size_t)tx * II;
        if (l4 == 0)      { xn0[mt] = *(const f32x4*)xp; xn1[mt] = *(const f32x4*)(xp + 4); }
        else if (l4 == 1) { xn0[mt] = *(const f32x4*)(xp + 8); }
      }
    }
    __builtin_amdgcn_sched_barrier(0);
  }

  // ================= epilogue: h(TT) logits + h_final ======================
  asm volatile("s_waitcnt vmcnt(0)" ::: "memory");
  wait_flags32(F, (unsigned)TT, &deadlock);
  {
    const uint8_t* hsrc = ws + ((TT & 1) ? HBUF_B : 0) + (size_t)c * HTILE_B;
#pragma unroll
    for (int it = 0; it < 8; ++it)
      __builtin_amdgcn_global_load_lds(
          (const GAS uint32_t*)(hsrc + it * 4096 + tid * 16),
          (LAS uint32_t*)(ldsA + it * 4096 + tid * 16), 16, 0, 17);
    asm volatile("s_waitcnt vmcnt(0)" ::: "memory");
    __builtin_amdgcn_s_barrier();

#pragma unroll
    for (int half = 0; half < 2; ++half) {
      const int lrw = half * 16 + erow;
      float s = 0.0f;
      half8 hv = *(const half8*)(ldsA + lrw * 1024 + ((l * 16) ^ ((lrw & 7) << 4)));
#pragma unroll
      for (int i = 0; i < 8; ++i) s += (float)hv[i] * wor8[i];
#pragma unroll
      for (int off = 1; off < 64; off <<= 1) s += __shfl_xor(s, off);
      if (l == 0) out[((size_t)(crb + lrw) * TT + (TT - 1)) * 2 + jj] = s + bo;
    }
  }

  // ---- h_final from fp32 carried state
#pragma unroll
  for (int mt = 0; mt < 2; ++mt)
#pragma unroll
    for (int q = 0; q < 4; ++q) {
      const int m = mt * 16 + l4 * 4 + q;
      out[(size_t)TB * TT * 2 + (size_t)(crb + m) * HH + pcol] = hprev[mt][q];
    }
}

extern "C" void kernel_launch(void* const* d_in, const int* in_sizes, int n_in,
                              void* d_out, int out_size, void* d_ws, size_t ws_size,
                              hipStream_t stream) {
  (void)in_sizes; (void)n_in; (void)out_size;
  if (ws_size < WS_USED) return;

  const float* hist  = (const float*)d_in[0];
  const float* w_ih  = (const float*)d_in[1];
  const float* w_hh  = (const float*)d_in[2];
  const float* w_out = (const float*)d_in[3];
  const float* b_out = (const float*)d_in[4];
  float* out = (float*)d_out;
  uint8_t* ws = (uint8_t*)d_ws;

  hipMemsetAsync(d_ws, 0, WS_USED, stream);   // h0 = 0, flag words

  void* args[] = {(void*)&hist, (void*)&w_ih, (void*)&w_hh, (void*)&w_out,
                  (void*)&b_out, (void*)&out, (void*)&ws};
  hipError_t e = hipLaunchCooperativeKernel((const void*)gru_persistent,
                                            dim3(NB), dim3(NT), args,
                                            (unsigned)LDSB, stream);
  if (e != hipSuccess) {
    // Fallback: plain launch. 256 blocks at 1/CU on 256 CUs co-reside; every
    // spin loop has a deadlock bail-out so this cannot hang.
    gru_persistent<<<dim3(NB), dim3(NT), LDSB, stream>>>(
        hist, w_ih, w_hh, w_out, b_out, out, ws);
  }
}